// Round 13
// baseline (180.117 us; speedup 1.0000x reference)
//
#include <hip/hip_runtime.h>
#include <math.h>

// Problem constants (from reference): DM=512, DS=16, K=4, EXPAND=1
#define DMc   512
#define DIc   512
#define DSc   16
#define KCc   4
#define DTRc  32          // (512+15)//16
#define NXDc  64          // DTR + 2*DS
#define LLEN  2048
#define BBc   4
#define BLT   (BBc*LLEN)  // 8192

// chunked scan config
#define NCH   128         // chunks per sequence
#define CLEN  (LLEN/NCH)  // 16

typedef __attribute__((ext_vector_type(8))) short short8;
typedef __attribute__((ext_vector_type(8))) unsigned short ushort8;
typedef __attribute__((ext_vector_type(4))) float f32x4;

__device__ __forceinline__ float sigmoidf_(float x) { return 1.f / (1.f + __expf(-x)); }

// round-to-nearest-even f32 -> bf16 bits
__device__ __forceinline__ unsigned short f2bf(float x) {
    unsigned int u = __float_as_uint(x);
    u = (u + 0x7FFFu + ((u >> 16) & 1u)) >> 16;
    return (unsigned short)u;
}

// ---------------------------------------------------------------------------
// fused f32 -> bf16 conversion of x, W_in, W_out (one launch, 8 elems/thread)
// ---------------------------------------------------------------------------
#define CN1 (BLT * DMc / 8)        // x
#define CN2 (1024 * DMc / 8)       // W_in
#define CN3 (DMc * DIc / 8)        // W_out
__global__ __launch_bounds__(256) void convert3_kernel(const float* __restrict__ x,
                                                       const float* __restrict__ Win,
                                                       const float* __restrict__ Wout,
                                                       unsigned short* __restrict__ xb,
                                                       unsigned short* __restrict__ Wb,
                                                       unsigned short* __restrict__ Wob)
{
    int i = blockIdx.x * 256 + threadIdx.x;
    const float* src; unsigned short* dst;
    if (i < CN1)                  { src = x;    dst = xb;  }
    else if (i < CN1 + CN2)       { src = Win;  dst = Wb;  i -= CN1; }
    else if (i < CN1 + CN2 + CN3) { src = Wout; dst = Wob; i -= CN1 + CN2; }
    else return;
    float4 a = ((const float4*)src)[2 * i];
    float4 b = ((const float4*)src)[2 * i + 1];
    ushort8 o;
    o[0] = f2bf(a.x); o[1] = f2bf(a.y); o[2] = f2bf(a.z); o[3] = f2bf(a.w);
    o[4] = f2bf(b.x); o[5] = f2bf(b.y); o[6] = f2bf(b.z); o[7] = f2bf(b.w);
    ((ushort8*)dst)[i] = o;
}

// ---------------------------------------------------------------------------
// f32 tiled GEMM: C[M,N] = A[M,K] * B[N,K]^T, strides lda/ldb/ldc.
// 64x64 tile, BK=16. EPI==2: v = softplus(v + bias[col]) (dt projection).
// ---------------------------------------------------------------------------
template<int EPI>
__global__ __launch_bounds__(256) void gemm_bt_f32(const float* __restrict__ A,
                                                   const float* __restrict__ Bw,
                                                   const float* __restrict__ bias,
                                                   float* __restrict__ C,
                                                   int M, int N, int Kd,
                                                   int lda, int ldb, int ldc)
{
    __shared__ float As[16][68];
    __shared__ float Bs[16][68];
    const int tid  = threadIdx.x;
    const int tx   = tid & 15;
    const int ty   = tid >> 4;
    const int arow = tid >> 2;
    const int akq  = (tid & 3) << 2;

    const float* Ab = A  + (size_t)(blockIdx.y * 64 + arow) * lda + akq;
    const float* Bb = Bw + (size_t)(blockIdx.x * 64 + arow) * ldb + akq;

    float acc[4][4] = {};

    for (int k0 = 0; k0 < Kd; k0 += 16) {
        float4 av = *(const float4*)(Ab + k0);
        float4 bv = *(const float4*)(Bb + k0);
        __syncthreads();
        As[akq + 0][arow] = av.x; As[akq + 1][arow] = av.y;
        As[akq + 2][arow] = av.z; As[akq + 3][arow] = av.w;
        Bs[akq + 0][arow] = bv.x; Bs[akq + 1][arow] = bv.y;
        Bs[akq + 2][arow] = bv.z; Bs[akq + 3][arow] = bv.w;
        __syncthreads();
#pragma unroll
        for (int k = 0; k < 16; ++k) {
            float4 a = *(const float4*)&As[k][ty << 2];
            float4 b = *(const float4*)&Bs[k][tx << 2];
            float ar[4] = {a.x, a.y, a.z, a.w};
            float br[4] = {b.x, b.y, b.z, b.w};
#pragma unroll
            for (int i = 0; i < 4; ++i)
#pragma unroll
                for (int j = 0; j < 4; ++j)
                    acc[i][j] += ar[i] * br[j];
        }
    }

    float4 bv = make_float4(0.f, 0.f, 0.f, 0.f);
    if (EPI == 2) bv = *(const float4*)(bias + blockIdx.x * 64 + (tx << 2));
#pragma unroll
    for (int i = 0; i < 4; ++i) {
        float v[4] = {acc[i][0], acc[i][1], acc[i][2], acc[i][3]};
        if (EPI == 2) {
            float bb[4] = {bv.x, bv.y, bv.z, bv.w};
#pragma unroll
            for (int j = 0; j < 4; ++j) {
                float s = v[j] + bb[j];
                v[j] = fmaxf(s, 0.f) + log1pf(__expf(-fabsf(s)));
            }
        }
        *(float4*)(C + (size_t)(blockIdx.y * 64 + (ty << 2) + i) * ldc
                     + blockIdx.x * 64 + (tx << 2)) = make_float4(v[0], v[1], v[2], v[3]);
    }
}

// ---------------------------------------------------------------------------
// bf16 MFMA GEMM: C[M,N] = A[M,K] * B[N,K]^T, f32 accumulate/output.
// 128x128 tile, BK=32, 4 waves (no swizzle — L3-resident working set).
// EPI==1: clip to [-1000,1000], NaN->0.
// ---------------------------------------------------------------------------
template<int EPI>
__global__ __launch_bounds__(256) void gemm_mfma(const unsigned short* __restrict__ A,
                                                 const unsigned short* __restrict__ Bw,
                                                 float* __restrict__ C,
                                                 int M, int N, int Kd)
{
    __shared__ short As[128][40];
    __shared__ short Bs[128][40];
    const int tid  = threadIdx.x;
    const int lane = tid & 63;
    const int wv   = tid >> 6;
    const int wr   = wv >> 1;
    const int wc   = wv & 1;
    const int fr   = lane & 15;
    const int fq   = lane >> 4;

    const int rowA0 = blockIdx.y * 128;
    const int rowB0 = blockIdx.x * 128;

    const int r0 = tid >> 2,        s0 = (tid & 3) << 3;
    const int r1 = (tid + 256) >> 2, s1 = s0;

    f32x4 acc[4][4];
#pragma unroll
    for (int m = 0; m < 4; ++m)
#pragma unroll
        for (int n = 0; n < 4; ++n) acc[m][n] = (f32x4){0.f, 0.f, 0.f, 0.f};

    for (int k0 = 0; k0 < Kd; k0 += 32) {
        short8 a0 = *(const short8*)(A  + (size_t)(rowA0 + r0) * Kd + k0 + s0);
        short8 a1 = *(const short8*)(A  + (size_t)(rowA0 + r1) * Kd + k0 + s1);
        short8 b0 = *(const short8*)(Bw + (size_t)(rowB0 + r0) * Kd + k0 + s0);
        short8 b1 = *(const short8*)(Bw + (size_t)(rowB0 + r1) * Kd + k0 + s1);
        __syncthreads();
        *(short8*)&As[r0][s0] = a0;
        *(short8*)&As[r1][s1] = a1;
        *(short8*)&Bs[r0][s0] = b0;
        *(short8*)&Bs[r1][s1] = b1;
        __syncthreads();

        short8 af[4], bf[4];
#pragma unroll
        for (int m = 0; m < 4; ++m)
            af[m] = *(const short8*)&As[wr * 64 + m * 16 + fr][fq << 3];
#pragma unroll
        for (int n = 0; n < 4; ++n)
            bf[n] = *(const short8*)&Bs[wc * 64 + n * 16 + fr][fq << 3];
#pragma unroll
        for (int m = 0; m < 4; ++m)
#pragma unroll
            for (int n = 0; n < 4; ++n)
                acc[m][n] = __builtin_amdgcn_mfma_f32_16x16x32_bf16(af[m], bf[n], acc[m][n], 0, 0, 0);
    }

    const int crow0 = rowA0 + wr * 64 + (fq << 2);
    const int ccol0 = rowB0 + wc * 64 + fr;
#pragma unroll
    for (int m = 0; m < 4; ++m)
#pragma unroll
        for (int n = 0; n < 4; ++n)
#pragma unroll
            for (int j = 0; j < 4; ++j) {
                float v = acc[m][n][j];
                if (EPI) v = (v != v) ? 0.f : fminf(fmaxf(v, -1000.f), 1000.f);
                C[(size_t)(crow0 + m * 16 + j) * N + ccol0 + n * 16] = v;
            }
}

// ---------------------------------------------------------------------------
// Fused conv + x_dbl GEMM: xdbl[M,64] = silu(conv(xz)) @ Wxp[64,512]^T.
// 64x64 tile, BK=16. A-tile elements computed on the fly during staging:
// xc[row][d] = silu(cb[d] + sum_k xz[row-3+k][d] * cw[d*4+k])  (causal, K=4)
// xc is never materialized in HBM.
// ---------------------------------------------------------------------------
__global__ __launch_bounds__(256) void xdbl_conv_kernel(const float* __restrict__ xz,
                                                        const float* __restrict__ cw,
                                                        const float* __restrict__ cb,
                                                        const float* __restrict__ Wxp,
                                                        float* __restrict__ xdbl)
{
    __shared__ float As[16][68];
    __shared__ float Bs[16][68];
    const int tid  = threadIdx.x;
    const int tx   = tid & 15;
    const int ty   = tid >> 4;
    const int arow = tid >> 2;
    const int akq  = (tid & 3) << 2;
    const int row0 = blockIdx.y * 64;
    const int gr   = row0 + arow;          // global row (sequence position)
    const int l    = gr & (LLEN - 1);      // position within sequence

    const float* Bb = Wxp + (size_t)arow * DIc + akq;

    float acc[4][4] = {};

    for (int k0 = 0; k0 < DIc; k0 += 16) {
        const int d0 = k0 + akq;           // this thread's 4 channels
        // conv weights/bias for channels d0..d0+3 (L2-hot, 16+4 floats)
        float cwa[4][4];
#pragma unroll
        for (int j = 0; j < 4; ++j) {
            float4 w = *(const float4*)(cw + (size_t)(d0 + j) * KCc);
            cwa[j][0] = w.x; cwa[j][1] = w.y; cwa[j][2] = w.z; cwa[j][3] = w.w;
        }
        float4 cbv = *(const float4*)(cb + d0);
        float s[4] = {cbv.x, cbv.y, cbv.z, cbv.w};
#pragma unroll
        for (int k = 0; k < KCc; ++k) {
            if (l - (KCc - 1) + k >= 0) {
                float4 v = *(const float4*)(xz + ((size_t)(gr - (KCc - 1) + k) << 10) + d0);
                s[0] += v.x * cwa[0][k]; s[1] += v.y * cwa[1][k];
                s[2] += v.z * cwa[2][k]; s[3] += v.w * cwa[3][k];
            }
        }
        float4 bv = *(const float4*)(Bb + k0);
        __syncthreads();
        As[akq + 0][arow] = s[0] * sigmoidf_(s[0]);
        As[akq + 1][arow] = s[1] * sigmoidf_(s[1]);
        As[akq + 2][arow] = s[2] * sigmoidf_(s[2]);
        As[akq + 3][arow] = s[3] * sigmoidf_(s[3]);
        Bs[akq + 0][arow] = bv.x; Bs[akq + 1][arow] = bv.y;
        Bs[akq + 2][arow] = bv.z; Bs[akq + 3][arow] = bv.w;
        __syncthreads();
#pragma unroll
        for (int k = 0; k < 16; ++k) {
            float4 a = *(const float4*)&As[k][ty << 2];
            float4 b = *(const float4*)&Bs[k][tx << 2];
            float ar[4] = {a.x, a.y, a.z, a.w};
            float br[4] = {b.x, b.y, b.z, b.w};
#pragma unroll
            for (int i = 0; i < 4; ++i)
#pragma unroll
                for (int j = 0; j < 4; ++j)
                    acc[i][j] += ar[i] * br[j];
        }
    }

#pragma unroll
    for (int i = 0; i < 4; ++i)
        *(float4*)(xdbl + (size_t)(row0 + (ty << 2) + i) * NXDc + (tx << 2))
            = make_float4(acc[i][0], acc[i][1], acc[i][2], acc[i][3]);
}

// ---------------------------------------------------------------------------
// Chunked parallel scan. dt f32 in dtz[row*512+d]; z at xz[row*1024+512+d];
// xc recomputed inline from xz (4-tap conv + SiLU, sliding window).
// hstate[b,c,s,d]: h_end after phase1, h_in after phase2 (f32).
// ---------------------------------------------------------------------------
__device__ __forceinline__ size_t hs_off(int b, int c, int s, int d) {
    return ((size_t)((b * NCH + c) * DSc + s) << 9) + d;
}

__global__ __launch_bounds__(256) void scan_phase1(const float* __restrict__ dtz,
                                                   const float* __restrict__ xz,
                                                   const float* __restrict__ cw,
                                                   const float* __restrict__ cb,
                                                   const float* __restrict__ xdbl,
                                                   const float* __restrict__ A_log,
                                                   float* __restrict__ hstate,
                                                   float* __restrict__ sdtbuf)
{
    int half = blockIdx.x & 1;
    int c    = (blockIdx.x >> 1) & (NCH - 1);
    int b    = blockIdx.x >> 8;
    int d    = (half << 8) + threadIdx.x;
    int row0 = b * LLEN + c * CLEN;

    __shared__ float bc[CLEN][32];   // [t][0:16]=B
    {
        int r = threadIdx.x >> 4, col = (threadIdx.x & 15) << 1;
        const float* src = xdbl + (size_t)(row0 + r) * NXDc + DTRc + col;
        bc[r][col] = src[0]; bc[r][col + 1] = src[1];
    }

    float A[DSc];
#pragma unroll
    for (int s = 0; s < DSc; ++s) A[s] = -__expf(A_log[d * DSc + s]);

    // conv params + sliding-window x values
    float w0 = cw[d * KCc], w1 = cw[d * KCc + 1], w2 = cw[d * KCc + 2], w3 = cw[d * KCc + 3];
    float cbv = cb[d];
    float xv[CLEN + 3];
#pragma unroll
    for (int i = 0; i < CLEN + 3; ++i) {
        xv[i] = (c == 0 && i < 3) ? 0.f
              : xz[((size_t)(row0 - 3 + i) << 10) + d];
    }
    float dtv[CLEN], xcv[CLEN];
#pragma unroll
    for (int t = 0; t < CLEN; ++t)
        dtv[t] = dtz[((size_t)(row0 + t) << 9) + d];
#pragma unroll
    for (int t = 0; t < CLEN; ++t) {
        float s = cbv + xv[t] * w0 + xv[t + 1] * w1 + xv[t + 2] * w2 + xv[t + 3] * w3;
        xcv[t] = s * sigmoidf_(s);
    }
    __syncthreads();

    float h[DSc] = {};
    float Sdt = 0.f;
#pragma unroll
    for (int t = 0; t < CLEN; ++t) {
        float dBx = dtv[t] * xcv[t];
        Sdt += dtv[t];
#pragma unroll
        for (int s = 0; s < DSc; ++s)
            h[s] = __expf(dtv[t] * A[s]) * h[s] + dBx * bc[t][s];
    }
#pragma unroll
    for (int s = 0; s < DSc; ++s) hstate[hs_off(b, c, s, d)] = h[s];
    sdtbuf[((size_t)(b * NCH + c) << 9) + d] = Sdt;
}

__global__ __launch_bounds__(64) void scan_phase2(float* __restrict__ hstate,
                                                  const float* __restrict__ sdtbuf,
                                                  const float* __restrict__ A_log)
{
    int gid = blockIdx.x * 64 + threadIdx.x;    // over B*DSc*DIc = 32768
    int d = gid & (DIc - 1);
    int s = (gid >> 9) & (DSc - 1);
    int b = gid >> 13;

    float A = -__expf(A_log[d * DSc + s]);
    float h = 0.f;
    for (int c = 0; c < NCH; ++c) {
        size_t o = hs_off(b, c, s, d);
        float he  = hstate[o];
        float Sdt = sdtbuf[((size_t)(b * NCH + c) << 9) + d];
        hstate[o] = h;
        h = __expf(A * Sdt) * h + he;
    }
}

__global__ __launch_bounds__(256) void scan_phase3(const float* __restrict__ dtz,
                                                   const float* __restrict__ xz,
                                                   const float* __restrict__ cw,
                                                   const float* __restrict__ cb,
                                                   const float* __restrict__ xdbl,
                                                   const float* __restrict__ hstate,
                                                   const float* __restrict__ A_log,
                                                   const float* __restrict__ Dp,
                                                   unsigned short* __restrict__ yb)
{
    int half = blockIdx.x & 1;
    int c    = (blockIdx.x >> 1) & (NCH - 1);
    int b    = blockIdx.x >> 8;
    int d    = (half << 8) + threadIdx.x;
    int row0 = b * LLEN + c * CLEN;

    __shared__ float bc[CLEN][32];   // [t][0:16]=B, [t][16:32]=C
    {
        int r = threadIdx.x >> 4, col = (threadIdx.x & 15) << 1;
        const float* src = xdbl + (size_t)(row0 + r) * NXDc + DTRc + col;
        bc[r][col] = src[0]; bc[r][col + 1] = src[1];
    }

    float A[DSc];
#pragma unroll
    for (int s = 0; s < DSc; ++s) A[s] = -__expf(A_log[d * DSc + s]);
    float Dv = Dp[d];

    float w0 = cw[d * KCc], w1 = cw[d * KCc + 1], w2 = cw[d * KCc + 2], w3 = cw[d * KCc + 3];
    float cbv = cb[d];
    float xv[CLEN + 3];
#pragma unroll
    for (int i = 0; i < CLEN + 3; ++i) {
        xv[i] = (c == 0 && i < 3) ? 0.f
              : xz[((size_t)(row0 - 3 + i) << 10) + d];
    }
    float dtv[CLEN], xcv[CLEN], zv[CLEN];
#pragma unroll
    for (int t = 0; t < CLEN; ++t) {
        dtv[t] = dtz[((size_t)(row0 + t) << 9) + d];
        zv[t]  = xz[((size_t)(row0 + t) << 10) + DIc + d];
    }
#pragma unroll
    for (int t = 0; t < CLEN; ++t) {
        float s = cbv + xv[t] * w0 + xv[t + 1] * w1 + xv[t + 2] * w2 + xv[t + 3] * w3;
        xcv[t] = s * sigmoidf_(s);
    }

    float h[DSc];
#pragma unroll
    for (int s = 0; s < DSc; ++s) h[s] = hstate[hs_off(b, c, s, d)];  // h_in
    __syncthreads();

#pragma unroll
    for (int t = 0; t < CLEN; ++t) {
        float dBx = dtv[t] * xcv[t];
        float acc = 0.f;
#pragma unroll
        for (int s = 0; s < DSc; ++s) {
            float dA = __expf(dtv[t] * A[s]);
            h[s] = dA * h[s] + dBx * bc[t][s];
            acc += h[s] * bc[t][DSc + s];
        }
        float yv = (acc + xcv[t] * Dv) * (zv[t] * sigmoidf_(zv[t]));
        yb[((size_t)(row0 + t) << 9) + d] = f2bf(yv);
    }
}

// ---------------------------------------------------------------------------
extern "C" void kernel_launch(void* const* d_in, const int* in_sizes, int n_in,
                              void* d_out, int out_size, void* d_ws, size_t ws_size,
                              hipStream_t stream)
{
    const float* x      = (const float*)d_in[0];
    const float* W_in   = (const float*)d_in[1];
    const float* conv_w = (const float*)d_in[2];
    const float* conv_b = (const float*)d_in[3];
    const float* W_xp   = (const float*)d_in[4];
    const float* W_dt   = (const float*)d_in[5];
    const float* b_dt   = (const float*)d_in[6];
    const float* A_log  = (const float*)d_in[7];
    const float* D_par  = (const float*)d_in[8];
    const float* W_out  = (const float*)d_in[9];
    float* out = (float*)d_out;

    float* ws   = (float*)d_ws;
    float* xz   = ws;                                   // [8192,1024] f32 (x | z), stays live
    float* xdbl = xz + (size_t)BLT * 1024;              // [8192,64]   f32
    float* dtz  = xdbl + (size_t)BLT * NXDc;            // [8192,512]  f32: dt
    unsigned short* xb  = (unsigned short*)(dtz + (size_t)BLT * DIc); // [8192,512] bf16 (x, then y)
    unsigned short* Wb  = xb + (size_t)BLT * DIc;       // [1024,512] bf16
    unsigned short* Wob = Wb + (size_t)1024 * DMc;      // [512,512]  bf16
    float* hstate = (float*)(Wob + (size_t)DMc * DIc);  // [4,128,16,512] f32
    float* sdtbuf = hstate + (size_t)BBc * NCH * DSc * DIc; // [4,128,512] f32

    // 0. f32 -> bf16 conversions (x, W_in, W_out) in one launch
    convert3_kernel<<<(CN1 + CN2 + CN3 + 255) / 256, 256, 0, stream>>>(
        x, W_in, W_out, xb, Wb, Wob);

    // 1. xz = x @ W_in^T      (M=8192, N=1024, K=512) via bf16 MFMA
    gemm_mfma<0><<<dim3(1024 / 128, BLT / 128), 256, 0, stream>>>(xb, Wb, xz, BLT, 1024, DMc);

    // 2. x_dbl = silu(conv(xz)) @ W_xproj^T  (conv fused into staging; no xc buffer)
    xdbl_conv_kernel<<<dim3(1, BLT / 64), 256, 0, stream>>>(xz, conv_w, conv_b, W_xp, xdbl);

    // 3. dt = softplus(x_dbl[:, :32] @ W_dt^T + b_dt) -> dtz
    gemm_bt_f32<2><<<dim3(DIc / 64, BLT / 64), 256, 0, stream>>>(xdbl, W_dt, b_dt, dtz,
                                                                 BLT, DIc, DTRc, NXDc, DTRc, DIc);

    // 4. chunked parallel scan (conv recomputed inline); y (bf16) into xb
    scan_phase1<<<BBc * NCH * 2, 256, 0, stream>>>(dtz, xz, conv_w, conv_b, xdbl,
                                                   A_log, hstate, sdtbuf);
    scan_phase2<<<(BBc * DSc * DIc) / 64, 64, 0, stream>>>(hstate, sdtbuf, A_log);
    scan_phase3<<<BBc * NCH * 2, 256, 0, stream>>>(dtz, xz, conv_w, conv_b, xdbl,
                                                   hstate, A_log, D_par, xb);

    // 5. out = clip(y @ W_out^T)  (M=8192, N=512, K=512) via bf16 MFMA
    gemm_mfma<1><<<dim3(DMc / 128, BLT / 128), 256, 0, stream>>>(xb, Wob, out, BLT, DMc, DMc);
}

// Round 14
// 170.327 us; speedup vs baseline: 1.0575x; 1.0575x over previous
//
#include <hip/hip_runtime.h>
#include <math.h>

// Problem constants (from reference): DM=512, DS=16, K=4, EXPAND=1
#define DMc   512
#define DIc   512
#define DSc   16
#define KCc   4
#define DTRc  32          // (512+15)//16
#define NXDc  64          // DTR + 2*DS
#define LLEN  2048
#define BBc   4
#define BLT   (BBc*LLEN)  // 8192

// chunked scan config
#define NCH   128         // chunks per sequence
#define CLEN  (LLEN/NCH)  // 16

typedef __attribute__((ext_vector_type(8))) short short8;
typedef __attribute__((ext_vector_type(8))) unsigned short ushort8;
typedef __attribute__((ext_vector_type(4))) float f32x4;

__device__ __forceinline__ float sigmoidf_(float x) { return 1.f / (1.f + __expf(-x)); }

// round-to-nearest-even f32 -> bf16 bits
__device__ __forceinline__ unsigned short f2bf(float x) {
    unsigned int u = __float_as_uint(x);
    u = (u + 0x7FFFu + ((u >> 16) & 1u)) >> 16;
    return (unsigned short)u;
}

// ---------------------------------------------------------------------------
// fused f32 -> bf16 conversion of x, W_in, W_out (one launch, 8 elems/thread)
// ---------------------------------------------------------------------------
#define CN1 (BLT * DMc / 8)        // x
#define CN2 (1024 * DMc / 8)       // W_in
#define CN3 (DMc * DIc / 8)        // W_out
__global__ __launch_bounds__(256) void convert3_kernel(const float* __restrict__ x,
                                                       const float* __restrict__ Win,
                                                       const float* __restrict__ Wout,
                                                       unsigned short* __restrict__ xb,
                                                       unsigned short* __restrict__ Wb,
                                                       unsigned short* __restrict__ Wob)
{
    int i = blockIdx.x * 256 + threadIdx.x;
    const float* src; unsigned short* dst;
    if (i < CN1)                  { src = x;    dst = xb;  }
    else if (i < CN1 + CN2)       { src = Win;  dst = Wb;  i -= CN1; }
    else if (i < CN1 + CN2 + CN3) { src = Wout; dst = Wob; i -= CN1 + CN2; }
    else return;
    float4 a = ((const float4*)src)[2 * i];
    float4 b = ((const float4*)src)[2 * i + 1];
    ushort8 o;
    o[0] = f2bf(a.x); o[1] = f2bf(a.y); o[2] = f2bf(a.z); o[3] = f2bf(a.w);
    o[4] = f2bf(b.x); o[5] = f2bf(b.y); o[6] = f2bf(b.z); o[7] = f2bf(b.w);
    ((ushort8*)dst)[i] = o;
}

// ---------------------------------------------------------------------------
// f32 tiled GEMM: C[M,N] = A[M,K] * B[N,K]^T, strides lda/ldb/ldc.
// 64x64 tile, BK=16. EPI==0: plain (x_dbl). EPI==2: softplus(v+bias) (dt).
// ---------------------------------------------------------------------------
template<int EPI>
__global__ __launch_bounds__(256) void gemm_bt_f32(const float* __restrict__ A,
                                                   const float* __restrict__ Bw,
                                                   const float* __restrict__ bias,
                                                   float* __restrict__ C,
                                                   int M, int N, int Kd,
                                                   int lda, int ldb, int ldc)
{
    __shared__ float As[16][68];
    __shared__ float Bs[16][68];
    const int tid  = threadIdx.x;
    const int tx   = tid & 15;
    const int ty   = tid >> 4;
    const int arow = tid >> 2;
    const int akq  = (tid & 3) << 2;

    const float* Ab = A  + (size_t)(blockIdx.y * 64 + arow) * lda + akq;
    const float* Bb = Bw + (size_t)(blockIdx.x * 64 + arow) * ldb + akq;

    float acc[4][4] = {};

    for (int k0 = 0; k0 < Kd; k0 += 16) {
        float4 av = *(const float4*)(Ab + k0);
        float4 bv = *(const float4*)(Bb + k0);
        __syncthreads();
        As[akq + 0][arow] = av.x; As[akq + 1][arow] = av.y;
        As[akq + 2][arow] = av.z; As[akq + 3][arow] = av.w;
        Bs[akq + 0][arow] = bv.x; Bs[akq + 1][arow] = bv.y;
        Bs[akq + 2][arow] = bv.z; Bs[akq + 3][arow] = bv.w;
        __syncthreads();
#pragma unroll
        for (int k = 0; k < 16; ++k) {
            float4 a = *(const float4*)&As[k][ty << 2];
            float4 b = *(const float4*)&Bs[k][tx << 2];
            float ar[4] = {a.x, a.y, a.z, a.w};
            float br[4] = {b.x, b.y, b.z, b.w};
#pragma unroll
            for (int i = 0; i < 4; ++i)
#pragma unroll
                for (int j = 0; j < 4; ++j)
                    acc[i][j] += ar[i] * br[j];
        }
    }

    float4 bv = make_float4(0.f, 0.f, 0.f, 0.f);
    if (EPI == 2) bv = *(const float4*)(bias + blockIdx.x * 64 + (tx << 2));
#pragma unroll
    for (int i = 0; i < 4; ++i) {
        float v[4] = {acc[i][0], acc[i][1], acc[i][2], acc[i][3]};
        if (EPI == 2) {
            float bb[4] = {bv.x, bv.y, bv.z, bv.w};
#pragma unroll
            for (int j = 0; j < 4; ++j) {
                float s = v[j] + bb[j];
                v[j] = fmaxf(s, 0.f) + log1pf(__expf(-fabsf(s)));
            }
        }
        *(float4*)(C + (size_t)(blockIdx.y * 64 + (ty << 2) + i) * ldc
                     + blockIdx.x * 64 + (tx << 2)) = make_float4(v[0], v[1], v[2], v[3]);
    }
}

// ---------------------------------------------------------------------------
// bf16 MFMA GEMM: C[M,N] = A[M,K] * B[N,K]^T, f32 accumulate/output.
// 128x128 tile, BK=32, 4 waves (no swizzle — L3-resident working set).
// EPI==1: clip to [-1000,1000], NaN->0.
// ---------------------------------------------------------------------------
template<int EPI>
__global__ __launch_bounds__(256) void gemm_mfma(const unsigned short* __restrict__ A,
                                                 const unsigned short* __restrict__ Bw,
                                                 float* __restrict__ C,
                                                 int M, int N, int Kd)
{
    __shared__ short As[128][40];
    __shared__ short Bs[128][40];
    const int tid  = threadIdx.x;
    const int lane = tid & 63;
    const int wv   = tid >> 6;
    const int wr   = wv >> 1;
    const int wc   = wv & 1;
    const int fr   = lane & 15;
    const int fq   = lane >> 4;

    const int rowA0 = blockIdx.y * 128;
    const int rowB0 = blockIdx.x * 128;

    const int r0 = tid >> 2,        s0 = (tid & 3) << 3;
    const int r1 = (tid + 256) >> 2, s1 = s0;

    f32x4 acc[4][4];
#pragma unroll
    for (int m = 0; m < 4; ++m)
#pragma unroll
        for (int n = 0; n < 4; ++n) acc[m][n] = (f32x4){0.f, 0.f, 0.f, 0.f};

    for (int k0 = 0; k0 < Kd; k0 += 32) {
        short8 a0 = *(const short8*)(A  + (size_t)(rowA0 + r0) * Kd + k0 + s0);
        short8 a1 = *(const short8*)(A  + (size_t)(rowA0 + r1) * Kd + k0 + s1);
        short8 b0 = *(const short8*)(Bw + (size_t)(rowB0 + r0) * Kd + k0 + s0);
        short8 b1 = *(const short8*)(Bw + (size_t)(rowB0 + r1) * Kd + k0 + s1);
        __syncthreads();
        *(short8*)&As[r0][s0] = a0;
        *(short8*)&As[r1][s1] = a1;
        *(short8*)&Bs[r0][s0] = b0;
        *(short8*)&Bs[r1][s1] = b1;
        __syncthreads();

        short8 af[4], bf[4];
#pragma unroll
        for (int m = 0; m < 4; ++m)
            af[m] = *(const short8*)&As[wr * 64 + m * 16 + fr][fq << 3];
#pragma unroll
        for (int n = 0; n < 4; ++n)
            bf[n] = *(const short8*)&Bs[wc * 64 + n * 16 + fr][fq << 3];
#pragma unroll
        for (int m = 0; m < 4; ++m)
#pragma unroll
            for (int n = 0; n < 4; ++n)
                acc[m][n] = __builtin_amdgcn_mfma_f32_16x16x32_bf16(af[m], bf[n], acc[m][n], 0, 0, 0);
    }

    const int crow0 = rowA0 + wr * 64 + (fq << 2);
    const int ccol0 = rowB0 + wc * 64 + fr;
#pragma unroll
    for (int m = 0; m < 4; ++m)
#pragma unroll
        for (int n = 0; n < 4; ++n)
#pragma unroll
            for (int j = 0; j < 4; ++j) {
                float v = acc[m][n][j];
                if (EPI) v = (v != v) ? 0.f : fminf(fmaxf(v, -1000.f), 1000.f);
                C[(size_t)(crow0 + m * 16 + j) * N + ccol0 + n * 16] = v;
            }
}

// ---------------------------------------------------------------------------
// Depthwise causal conv (K=4) + bias + SiLU on the first DI lanes of xz.
// (separate kernel — fusing this into the xdbl GEMM staging cost 3x, r13)
// ---------------------------------------------------------------------------
__global__ __launch_bounds__(256) void conv_silu_kernel(const float* __restrict__ xz,
                                                        const float* __restrict__ cw,
                                                        const float* __restrict__ cb,
                                                        float* __restrict__ xc)
{
    int gid = blockIdx.x * 256 + threadIdx.x;       // over B*L*DI
    int d = gid & (DIc - 1);
    int l = (gid >> 9) & (LLEN - 1);
    int b = gid >> 20;
    float s = cb[d];
#pragma unroll
    for (int k = 0; k < KCc; ++k) {
        int ls = l + k - (KCc - 1);
        if (ls >= 0)
            s += xz[((size_t)(b * LLEN + ls) << 10) + d] * cw[d * KCc + k];
    }
    xc[gid] = s * sigmoidf_(s);
}

// ---------------------------------------------------------------------------
// Chunked parallel scan (r13 structure). dt f32 in dtz[row*512+d];
// z at xz[row*1024+512+d]; xc recomputed inline from xz (4-tap conv + SiLU).
// hstate[b,c,s,d]: h_end after phase1, h_in after phase2 (f32).
// ---------------------------------------------------------------------------
__device__ __forceinline__ size_t hs_off(int b, int c, int s, int d) {
    return ((size_t)((b * NCH + c) * DSc + s) << 9) + d;
}

__global__ __launch_bounds__(256) void scan_phase1(const float* __restrict__ dtz,
                                                   const float* __restrict__ xz,
                                                   const float* __restrict__ cw,
                                                   const float* __restrict__ cb,
                                                   const float* __restrict__ xdbl,
                                                   const float* __restrict__ A_log,
                                                   float* __restrict__ hstate,
                                                   float* __restrict__ sdtbuf)
{
    int half = blockIdx.x & 1;
    int c    = (blockIdx.x >> 1) & (NCH - 1);
    int b    = blockIdx.x >> 8;
    int d    = (half << 8) + threadIdx.x;
    int row0 = b * LLEN + c * CLEN;

    __shared__ float bc[CLEN][32];   // [t][0:16]=B
    {
        int r = threadIdx.x >> 4, col = (threadIdx.x & 15) << 1;
        const float* src = xdbl + (size_t)(row0 + r) * NXDc + DTRc + col;
        bc[r][col] = src[0]; bc[r][col + 1] = src[1];
    }

    float A[DSc];
#pragma unroll
    for (int s = 0; s < DSc; ++s) A[s] = -__expf(A_log[d * DSc + s]);

    // conv params + sliding-window x values
    float w0 = cw[d * KCc], w1 = cw[d * KCc + 1], w2 = cw[d * KCc + 2], w3 = cw[d * KCc + 3];
    float cbv = cb[d];
    float xv[CLEN + 3];
#pragma unroll
    for (int i = 0; i < CLEN + 3; ++i) {
        xv[i] = (c == 0 && i < 3) ? 0.f
              : xz[((size_t)(row0 - 3 + i) << 10) + d];
    }
    float dtv[CLEN], xcv[CLEN];
#pragma unroll
    for (int t = 0; t < CLEN; ++t)
        dtv[t] = dtz[((size_t)(row0 + t) << 9) + d];
#pragma unroll
    for (int t = 0; t < CLEN; ++t) {
        float s = cbv + xv[t] * w0 + xv[t + 1] * w1 + xv[t + 2] * w2 + xv[t + 3] * w3;
        xcv[t] = s * sigmoidf_(s);
    }
    __syncthreads();

    float h[DSc] = {};
    float Sdt = 0.f;
#pragma unroll
    for (int t = 0; t < CLEN; ++t) {
        float dBx = dtv[t] * xcv[t];
        Sdt += dtv[t];
#pragma unroll
        for (int s = 0; s < DSc; ++s)
            h[s] = __expf(dtv[t] * A[s]) * h[s] + dBx * bc[t][s];
    }
#pragma unroll
    for (int s = 0; s < DSc; ++s) hstate[hs_off(b, c, s, d)] = h[s];
    sdtbuf[((size_t)(b * NCH + c) << 9) + d] = Sdt;
}

__global__ __launch_bounds__(64) void scan_phase2(float* __restrict__ hstate,
                                                  const float* __restrict__ sdtbuf,
                                                  const float* __restrict__ A_log)
{
    int gid = blockIdx.x * 64 + threadIdx.x;    // over B*DSc*DIc = 32768
    int d = gid & (DIc - 1);
    int s = (gid >> 9) & (DSc - 1);
    int b = gid >> 13;

    float A = -__expf(A_log[d * DSc + s]);
    float h = 0.f;
    for (int c = 0; c < NCH; ++c) {
        size_t o = hs_off(b, c, s, d);
        float he  = hstate[o];
        float Sdt = sdtbuf[((size_t)(b * NCH + c) << 9) + d];
        hstate[o] = h;
        h = __expf(A * Sdt) * h + he;
    }
}

__global__ __launch_bounds__(256) void scan_phase3(const float* __restrict__ dtz,
                                                   const float* __restrict__ xz,
                                                   const float* __restrict__ cw,
                                                   const float* __restrict__ cb,
                                                   const float* __restrict__ xdbl,
                                                   const float* __restrict__ hstate,
                                                   const float* __restrict__ A_log,
                                                   const float* __restrict__ Dp,
                                                   unsigned short* __restrict__ yb)
{
    int half = blockIdx.x & 1;
    int c    = (blockIdx.x >> 1) & (NCH - 1);
    int b    = blockIdx.x >> 8;
    int d    = (half << 8) + threadIdx.x;
    int row0 = b * LLEN + c * CLEN;

    __shared__ float bc[CLEN][32];   // [t][0:16]=B, [t][16:32]=C
    {
        int r = threadIdx.x >> 4, col = (threadIdx.x & 15) << 1;
        const float* src = xdbl + (size_t)(row0 + r) * NXDc + DTRc + col;
        bc[r][col] = src[0]; bc[r][col + 1] = src[1];
    }

    float A[DSc];
#pragma unroll
    for (int s = 0; s < DSc; ++s) A[s] = -__expf(A_log[d * DSc + s]);
    float Dv = Dp[d];

    float w0 = cw[d * KCc], w1 = cw[d * KCc + 1], w2 = cw[d * KCc + 2], w3 = cw[d * KCc + 3];
    float cbv = cb[d];
    float xv[CLEN + 3];
#pragma unroll
    for (int i = 0; i < CLEN + 3; ++i) {
        xv[i] = (c == 0 && i < 3) ? 0.f
              : xz[((size_t)(row0 - 3 + i) << 10) + d];
    }
    float dtv[CLEN], xcv[CLEN], zv[CLEN];
#pragma unroll
    for (int t = 0; t < CLEN; ++t) {
        dtv[t] = dtz[((size_t)(row0 + t) << 9) + d];
        zv[t]  = xz[((size_t)(row0 + t) << 10) + DIc + d];
    }
#pragma unroll
    for (int t = 0; t < CLEN; ++t) {
        float s = cbv + xv[t] * w0 + xv[t + 1] * w1 + xv[t + 2] * w2 + xv[t + 3] * w3;
        xcv[t] = s * sigmoidf_(s);
    }

    float h[DSc];
#pragma unroll
    for (int s = 0; s < DSc; ++s) h[s] = hstate[hs_off(b, c, s, d)];  // h_in
    __syncthreads();

#pragma unroll
    for (int t = 0; t < CLEN; ++t) {
        float dBx = dtv[t] * xcv[t];
        float acc = 0.f;
#pragma unroll
        for (int s = 0; s < DSc; ++s) {
            float dA = __expf(dtv[t] * A[s]);
            h[s] = dA * h[s] + dBx * bc[t][s];
            acc += h[s] * bc[t][DSc + s];
        }
        float yv = (acc + xcv[t] * Dv) * (zv[t] * sigmoidf_(zv[t]));
        yb[((size_t)(row0 + t) << 9) + d] = f2bf(yv);
    }
}

// ---------------------------------------------------------------------------
extern "C" void kernel_launch(void* const* d_in, const int* in_sizes, int n_in,
                              void* d_out, int out_size, void* d_ws, size_t ws_size,
                              hipStream_t stream)
{
    const float* x      = (const float*)d_in[0];
    const float* W_in   = (const float*)d_in[1];
    const float* conv_w = (const float*)d_in[2];
    const float* conv_b = (const float*)d_in[3];
    const float* W_xp   = (const float*)d_in[4];
    const float* W_dt   = (const float*)d_in[5];
    const float* b_dt   = (const float*)d_in[6];
    const float* A_log  = (const float*)d_in[7];
    const float* D_par  = (const float*)d_in[8];
    const float* W_out  = (const float*)d_in[9];
    float* out = (float*)d_out;

    float* ws   = (float*)d_ws;
    float* xz   = ws;                                   // [8192,1024] f32 (x | z), stays live
    float* xc   = xz + (size_t)BLT * 1024;              // [8192,512]  f32 (conv output)
    float* xdbl = xc + (size_t)BLT * DIc;               // [8192,64]   f32
    float* dtz  = xdbl + (size_t)BLT * NXDc;            // [8192,512]  f32: dt
    unsigned short* xb  = (unsigned short*)(dtz + (size_t)BLT * DIc); // [8192,512] bf16 (x, then y)
    unsigned short* Wb  = xb + (size_t)BLT * DIc;       // [1024,512] bf16
    unsigned short* Wob = Wb + (size_t)1024 * DMc;      // [512,512]  bf16
    float* hstate = (float*)(Wob + (size_t)DMc * DIc);  // [4,128,16,512] f32
    float* sdtbuf = hstate + (size_t)BBc * NCH * DSc * DIc; // [4,128,512] f32

    // 0. f32 -> bf16 conversions (x, W_in, W_out) in one launch
    convert3_kernel<<<(CN1 + CN2 + CN3 + 255) / 256, 256, 0, stream>>>(
        x, W_in, W_out, xb, Wb, Wob);

    // 1. xz = x @ W_in^T      (M=8192, N=1024, K=512) via bf16 MFMA
    gemm_mfma<0><<<dim3(1024 / 128, BLT / 128), 256, 0, stream>>>(xb, Wb, xz, BLT, 1024, DMc);

    // 2. depthwise causal conv + SiLU -> xc
    conv_silu_kernel<<<(BLT * DIc) / 256, 256, 0, stream>>>(xz, conv_w, conv_b, xc);

    // 3. x_dbl = xc @ W_xproj^T   (M=8192, N=64, K=512)
    gemm_bt_f32<0><<<dim3(1, BLT / 64), 256, 0, stream>>>(xc, W_xp, nullptr, xdbl,
                                                          BLT, NXDc, DIc, DIc, DIc, NXDc);

    // 4. dt = softplus(x_dbl[:, :32] @ W_dt^T + b_dt) -> dtz
    gemm_bt_f32<2><<<dim3(DIc / 64, BLT / 64), 256, 0, stream>>>(xdbl, W_dt, b_dt, dtz,
                                                                 BLT, DIc, DTRc, NXDc, DTRc, DIc);

    // 5. chunked parallel scan (conv recomputed inline); y (bf16) into xb
    scan_phase1<<<BBc * NCH * 2, 256, 0, stream>>>(dtz, xz, conv_w, conv_b, xdbl,
                                                   A_log, hstate, sdtbuf);
    scan_phase2<<<(BBc * DSc * DIc) / 64, 64, 0, stream>>>(hstate, sdtbuf, A_log);
    scan_phase3<<<BBc * NCH * 2, 256, 0, stream>>>(dtz, xz, conv_w, conv_b, xdbl,
                                                   hstate, A_log, D_par, xb);

    // 6. out = clip(y @ W_out^T)  (M=8192, N=512, K=512) via bf16 MFMA
    gemm_mfma<1><<<dim3(DMc / 128, BLT / 128), 256, 0, stream>>>(xb, Wob, out, BLT, DMc, DMc);
}